// Round 2
// baseline (2074.560 us; speedup 1.0000x reference)
//
#include <hip/hip_runtime.h>

#define NPATH 15
#define TOTCG 615
#define TOTD  179

// path tables: PATHS enumeration order of the reference
constexpr int PI_[NPATH]    = {0,0,0,1,1,1,1,1,1,2,2,2,2,2,2};
constexpr int PF_[NPATH]    = {0,1,2,0,1,1,1,2,2,0,1,1,2,2,2};
constexpr int PO_[NPATH]    = {0,1,2,1,0,1,2,1,2,2,1,2,0,1,2};
constexpr int PSLOT_[NPATH] = {0,0,0,1,1,2,1,3,2,3,4,4,2,5,5};
// cumulative size (2i+1)(2f+1)(2o+1)
constexpr int CGOFF_[NPATH] = {0,1,10,35,44,53,80,125,170,245,270,315,390,415,490};
// cumulative size (2i+1)(2o+1)  (D entries)
constexpr int EBASE_[NPATH] = {0,1,4,9,18,21,30,45,54,69,94,109,134,139,154};
// cumulative size (2i+1)(2f+1)  (complex CG tasks)
constexpr int CB_[NPATH]    = {0,1,4,9,12,21,30,39,54,69,74,89,104,129,154};

// ws float offsets (small region)
#define OFF_CG 0
#define OFF_CW 1024
#define OFF_CB 1280
#define OFF_DT 1536
#define OFF_H  4096

__device__ inline float sspf(float v){
  float a = fabsf(v);
  return fmaxf(v, 0.f) + log1pf(expf(-a)) - 0.6931471805599453f;
}

__device__ inline double dfact_(int n){ double r=1.0; for(int i=2;i<=n;++i) r*=(double)i; return r; }

__device__ double cgc_(int j1,int j2,int j3,int m1,int m2,int m3){
  double pre = sqrt((2.0*j3+1.0)*dfact_(j1+j2-j3)*dfact_(j1-j2+j3)*dfact_(-j1+j2+j3)/dfact_(j1+j2+j3+1));
  pre *= sqrt(dfact_(j3+m3)*dfact_(j3-m3)*dfact_(j1-m1)*dfact_(j1+m1)*dfact_(j2-m2)*dfact_(j2+m2));
  double s=0.0;
  for(int k=0;k<=j1+j2-j3;++k){
    int d1=j1+j2-j3-k, d2=j1-m1-k, d3=j2+m2-k, d4=j3-j2+m1+k, d5=j3-j1-m2+k;
    if(d1<0||d2<0||d3<0||d4<0||d5<0) continue;
    double den = dfact_(k)*dfact_(d1)*dfact_(d2)*dfact_(d3)*dfact_(d4)*dfact_(d5);
    s += ((k&1)? -1.0:1.0)/den;
  }
  return pre*s;
}

// ---- K0: CG tables (exact replica of _cg_real), D-table, collapsed head linear ----
__global__ __launch_bounds__(256) void k_setup(const float* __restrict__ d2w, const float* __restrict__ d2b,
                        const float* __restrict__ d3w, const float* __restrict__ d3b,
                        float* __restrict__ ws){
  __shared__ double sC[TOTCG], sRe[TOTCG], sIm[TOTCG];
  __shared__ double sUr[35], sUi[35];
  const int tid = threadIdx.x;
  for (int t=tid; t<TOTCG; t+=256) sC[t]=0.0;
  if (tid==0){
    for (int t=0;t<35;t++){ sUr[t]=0.0; sUi[t]=0.0; }
    const double s2 = 0.70710678118654752440;
    sUr[0] = 1.0; // l=0
    for (int l=1;l<=2;l++){
      const int off = (l==1)?1:10;
      const int n = 2*l+1;
      sUr[off + l*n + l] = 1.0;
      for (int m=1;m<=l;m++){
        double sg = (m&1)? -1.0:1.0;
        sUr[off + (l+m)*n + (l+m)] = sg*s2;
        sUi[off + (l+m)*n + (l-m)] = sg*s2;
        sUr[off + (l-m)*n + (l+m)] = s2;
        sUi[off + (l-m)*n + (l-m)] = -s2;
      }
    }
  }
  __syncthreads();
  // phase A: complex-basis CG values
  for (int t=tid; t<179; t+=256){
    int p=0;
    for (int q=1;q<NPATH;q++) if (t>=CB_[q]) p=q;
    const int j1=PI_[p], j2=PF_[p], j3=PO_[p];
    const int n2=2*j2+1, n3=2*j3+1;
    const int loc = t - CB_[p];
    const int i1 = loc/n2, i2 = loc%n2;
    const int m1=i1-j1, m2=i2-j2, m3=m1+m2;
    if (m3>=-j3 && m3<=j3)
      sC[CGOFF_[p] + (i1*n2+i2)*n3 + (m3+j3)] = cgc_(j1,j2,j3,m1,m2,m3);
  }
  __syncthreads();
  // phase C: real transform
  for (int t=tid; t<TOTCG; t+=256){
    int p=0;
    for (int q=1;q<NPATH;q++) if (t>=CGOFF_[q]) p=q;
    const int j1=PI_[p], j2=PF_[p], j3=PO_[p];
    const int n1=2*j1+1, n2=2*j2+1, n3=2*j3+1;
    const int loc = t - CGOFF_[p];
    const int Cc = loc % n3;
    const int Bb = (loc/n3) % n2;
    const int A  = loc/(n3*n2);
    const int u1o = (j1==0)?0:((j1==1)?1:10);
    const int u2o = (j2==0)?0:((j2==1)?1:10);
    const int u3o = (j3==0)?0:((j3==1)?1:10);
    double sre=0.0, sim=0.0;
    for (int a=0;a<n1;a++){
      const double u1r = sUr[u1o + a*n1 + A], u1i = sUi[u1o + a*n1 + A];
      if (u1r==0.0 && u1i==0.0) continue;
      for (int b=0;b<n2;b++){
        const double u2r = sUr[u2o + b*n2 + Bb], u2i = sUi[u2o + b*n2 + Bb];
        if (u2r==0.0 && u2i==0.0) continue;
        const double qr = u1r*u2r - u1i*u2i;
        const double qi = u1r*u2i + u1i*u2r;
        const double* cp = &sC[CGOFF_[p] + (a*n2+b)*n3];
        for (int cidx=0;cidx<n3;cidx++){
          const double v = cp[cidx];
          if (v==0.0) continue;
          const double u3r = sUr[u3o + cidx*n3 + Cc], u3i = -sUi[u3o + cidx*n3 + Cc];
          sre += v*(qr*u3r - qi*u3i);
          sim += v*(qr*u3i + qi*u3r);
        }
      }
    }
    sRe[t]=sre; sIm[t]=sim;
  }
  __syncthreads();
  // phase D: per-path imag/real choice, write to ws
  if (tid < NPATH){
    const int p=tid;
    const int sz = ((p==NPATH-1)? TOTCG : CGOFF_[p+1]) - CGOFF_[p];
    double mxr=0.0, mxi=0.0;
    for (int t=0;t<sz;t++){
      mxr = fmax(mxr, fabs(sRe[CGOFF_[p]+t]));
      mxi = fmax(mxi, fabs(sIm[CGOFF_[p]+t]));
    }
    const bool useim = mxi > mxr;
    for (int t=0;t<sz;t++)
      ws[OFF_CG + CGOFF_[p]+t] = (float)(useim? sIm[CGOFF_[p]+t] : sRe[CGOFF_[p]+t]);
  }
  if (tid==16){
    int2* dt = (int2*)(ws + OFF_DT);
    int e=0;
    for (int p=0;p<NPATH;p++){
      const int i=PI_[p], f=PF_[p], o=PO_[p];
      const int n2=2*f+1, n3=2*o+1;
      for (int mi=0;mi<2*i+1;mi++)
        for (int k=0;k<n3;k++)
          dt[e++] = make_int2(CGOFF_[p] + mi*n2*n3 + k, n2 | (n3<<8) | ((f*f)<<16));
    }
  }
  if (tid<250){
    float acc=0.f;
    for (int k=0;k<150;k++) acc += d3w[k]*d2w[k*250+tid];
    ws[OFF_CW+tid]=acc;
  }
  if (tid==255){
    float acc = d3b[0];
    for (int k=0;k<150;k++) acc += d3w[k]*d2b[k];
    ws[OFF_CB]=acc;
  }
}

// ---- K1: h = x @ lin1_w.T + b ----
__global__ __launch_bounds__(256) void k_embed(const float* __restrict__ x, const float* __restrict__ w,
                       const float* __restrict__ b, float* __restrict__ h, int N){
  const int idx = blockIdx.x*256 + threadIdx.x;
  if (idx >= N*40) return;
  const int n = idx/40, c = idx - n*40;
  float acc = b[c];
  const float* xr = x + (size_t)n*20;
  const float* wr = w + c*20;
  #pragma unroll
  for (int k=0;k<20;k++) acc += xr[k]*wr[k];
  h[idx] = acc;
}

// ---- K2: conv1 (CG = identity), one wave per edge, atomic scatter ----
__global__ __launch_bounds__(256) void k_conv1(const int* __restrict__ ei, const float* __restrict__ ea,
    const float* __restrict__ rw1, const float* __restrict__ rb1,
    const float* __restrict__ rw2, const float* __restrict__ rb2,
    const float* __restrict__ h, float* __restrict__ outs, int E){
  __shared__ float sh1[4][36];
  const int wv = threadIdx.x >> 6;
  const int lane = threadIdx.x & 63;
  const int e = blockIdx.x*4 + wv;
  const bool act = e < E;
  int src=0,dst=0;
  float Y10=0,Y11=0,Y12=0, Y20=0,Y21=0,Y22=0,Y23=0,Y24=0;
  float g[12];
  if (act){
    src = ei[e]; dst = ei[E+e];
    const float ax = ea[3*e], ay = ea[3*e+1], az = ea[3*e+2];
    const float r = sqrtf(ax*ax+ay*ay+az*az + 1e-12f);
    const float inv = 1.f/r;
    const float X = ax*inv, Yv = ay*inv, Z = az*inv;
    Y10 = 0.48860251f*Yv; Y11 = 0.48860251f*Z; Y12 = 0.48860251f*X;
    Y20 = 1.09254843f*X*Yv; Y21 = 1.09254843f*Yv*Z; Y22 = 0.31539157f*(3.f*Z*Z-1.f);
    Y23 = 1.09254843f*X*Z; Y24 = 0.54627422f*(X*X-Yv*Yv);
    const float t = r * (11.f/5.f);
    #pragma unroll
    for (int bb=0;bb<12;bb++){ const float d = t - (float)bb; g[bb] = expf(-d*d); }
    const int grp = lane >> 4, jj = lane & 15;
    if (grp < 3 && jj < 12){
      float acc = rb1[grp*12+jj];
      #pragma unroll
      for (int bb=0;bb<12;bb++) acc += g[bb]*rw1[(grp*12+bb)*12+jj];
      sh1[wv][grp*12+jj] = fmaxf(acc, 0.f);
    }
  }
  __syncthreads();
  if (!act) return;
  const int c = lane;
  if (c >= 40) return;
  float w0 = rb2[c], w1 = rb2[40+c], w2 = rb2[80+c];
  #pragma unroll
  for (int j=0;j<12;j++){
    w0 += sh1[wv][j]    * rw2[j*40+c];
    w1 += sh1[wv][12+j] * rw2[(12+j)*40+c];
    w2 += sh1[wv][24+j] * rw2[(24+j)*40+c];
  }
  const float hv = h[(size_t)src*40+c];
  float* ob = outs + (size_t)dst*360;
  atomicAdd(ob + c, hv*w0*0.28209479f);
  const float f1 = hv*w1;
  atomicAdd(ob + 40 + c,  f1*Y10);
  atomicAdd(ob + 80 + c,  f1*Y11);
  atomicAdd(ob + 120 + c, f1*Y12);
  const float f2 = hv*w2;
  atomicAdd(ob + 160 + c, f2*Y20);
  atomicAdd(ob + 200 + c, f2*Y21);
  atomicAdd(ob + 240 + c, f2*Y22);
  atomicAdd(ob + 280 + c, f2*Y23);
  atomicAdd(ob + 320 + c, f2*Y24);
}

// ---- K3: per-node norm -> lin2 -> nonlin -> lin3 (in place) ----
__global__ __launch_bounds__(256) void k_node(float* __restrict__ outs,
    const float* __restrict__ w2g, const float* __restrict__ b20,
    const float* __restrict__ w3g, const float* __restrict__ b30, int N){
  __shared__ float sf[4][360];
  const int wv = threadIdx.x>>6, lane = threadIdx.x&63;
  const int n = blockIdx.x*4 + wv;
  const bool ok = (n < N);
  float* op = outs + (size_t)n*360;
  if (ok) for (int t=lane;t<360;t+=64) sf[wv][t]=op[t];
  __syncthreads();
  if (ok && lane<40){
    const int cc=lane;
    const float v0=sf[wv][cc];
    sf[wv][cc] = v0/(fabsf(v0)+1e-8f);
    float s1=0.f;
    #pragma unroll
    for (int mm=1;mm<4;mm++){ const float v=sf[wv][mm*40+cc]; s1+=v*v; }
    const float i1=1.f/(sqrtf(s1)+1e-8f);
    #pragma unroll
    for (int mm=1;mm<4;mm++) sf[wv][mm*40+cc]*=i1;
    float s2=0.f;
    #pragma unroll
    for (int mm=4;mm<9;mm++){ const float v=sf[wv][mm*40+cc]; s2+=v*v; }
    const float i2=1.f/(sqrtf(s2)+1e-8f);
    #pragma unroll
    for (int mm=4;mm<9;mm++) sf[wv][mm*40+cc]*=i2;
  }
  __syncthreads();
  float a[9]={0,0,0,0,0,0,0,0,0};
  if (ok && lane<40){
    const int o=lane;
    const float* w0r = w2g + o*40;
    const float* w1r = w2g + 1600 + o*40;
    const float* w2r = w2g + 3200 + o*40;
    for (int c2=0;c2<40;c2++){
      const float wa=w0r[c2];
      a[0]+=sf[wv][c2]*wa;
      const float wb=w1r[c2];
      a[1]+=sf[wv][40+c2]*wb; a[2]+=sf[wv][80+c2]*wb; a[3]+=sf[wv][120+c2]*wb;
      const float wc=w2r[c2];
      a[4]+=sf[wv][160+c2]*wc; a[5]+=sf[wv][200+c2]*wc; a[6]+=sf[wv][240+c2]*wc;
      a[7]+=sf[wv][280+c2]*wc; a[8]+=sf[wv][320+c2]*wc;
    }
    a[0]=sspf(a[0]+b20[o]);
    const float n1=sqrtf(a[1]*a[1]+a[2]*a[2]+a[3]*a[3]+1e-12f);
    float sc=sspf(n1)/(n1+1e-8f);
    a[1]*=sc; a[2]*=sc; a[3]*=sc;
    const float n2v=sqrtf(a[4]*a[4]+a[5]*a[5]+a[6]*a[6]+a[7]*a[7]+a[8]*a[8]+1e-12f);
    sc=sspf(n2v)/(n2v+1e-8f);
    a[4]*=sc; a[5]*=sc; a[6]*=sc; a[7]*=sc; a[8]*=sc;
  }
  __syncthreads();
  if (ok && lane<40){
    #pragma unroll
    for (int mm=0;mm<9;mm++) sf[wv][mm*40+lane]=a[mm];
  }
  __syncthreads();
  if (ok && lane<40){
    const int o=lane;
    float b[9]={0,0,0,0,0,0,0,0,0};
    const float* w0r = w3g + o*40;
    const float* w1r = w3g + 1600 + o*40;
    const float* w2r = w3g + 3200 + o*40;
    for (int c2=0;c2<40;c2++){
      const float wa=w0r[c2];
      b[0]+=sf[wv][c2]*wa;
      const float wb=w1r[c2];
      b[1]+=sf[wv][40+c2]*wb; b[2]+=sf[wv][80+c2]*wb; b[3]+=sf[wv][120+c2]*wb;
      const float wc=w2r[c2];
      b[4]+=sf[wv][160+c2]*wc; b[5]+=sf[wv][200+c2]*wc; b[6]+=sf[wv][240+c2]*wc;
      b[7]+=sf[wv][280+c2]*wc; b[8]+=sf[wv][320+c2]*wc;
    }
    b[0]+=b30[o];
    #pragma unroll
    for (int mm=0;mm<9;mm++) op[mm*40+o]=b[mm];
  }
}

// ---- K4: conv2, one wave per edge, skip dst%4!=0 ----
template<int P>
__device__ inline void do_path(const float* __restrict__ rb2, const float* __restrict__ rw2,
                               const float* sh1, const float* sD, const float* xi, int c, int n4,
                               float* __restrict__ tmp0, float* __restrict__ tmp1, float* __restrict__ tmp2){
  constexpr int I = PI_[P], O = PO_[P], S = PSLOT_[P];
  constexpr int NO = 2*O+1;
  float wp = rb2[P*40+c];
  #pragma unroll
  for (int j=0;j<12;j++) wp += sh1[P*12+j]*rw2[(P*12+j)*40+c];
  float t[NO];
  #pragma unroll
  for (int k=0;k<NO;k++) t[k]=0.f;
  #pragma unroll
  for (int mi=0;mi<2*I+1;mi++){
    const float xv = xi[I*I+mi];
    #pragma unroll
    for (int k=0;k<NO;k++) t[k] += sD[EBASE_[P] + mi*NO + k]*xv;
  }
  float* dp;
  if constexpr (O==0) dp = tmp0 + (size_t)n4*120 + S*40 + c;
  else if constexpr (O==1) dp = tmp1 + (size_t)n4*720 + S*120 + c;
  else dp = tmp2 + (size_t)n4*1200 + S*200 + c;
  #pragma unroll
  for (int k=0;k<NO;k++) atomicAdd(dp + k*40, t[k]*wp);
}

__global__ __launch_bounds__(64) void k_conv2(const int* __restrict__ ei, const float* __restrict__ ea,
    const float* __restrict__ rw1, const float* __restrict__ rb1,
    const float* __restrict__ rw2, const float* __restrict__ rb2,
    const float* __restrict__ outs, const float* __restrict__ cgws, const int2* __restrict__ dtab,
    float* __restrict__ tmp0, float* __restrict__ tmp1, float* __restrict__ tmp2, int E){
  __shared__ float s_ym[12];
  __shared__ float s_h1[NPATH*12];
  __shared__ float s_D[TOTD];
  const int e = blockIdx.x;
  const int lane = threadIdx.x;
  const int dst = ei[E+e];
  if (dst & 3) return;
  const int src = ei[e];
  const int n4 = dst >> 2;
  const float ax = ea[3*e], ay = ea[3*e+1], az = ea[3*e+2];
  const float r = sqrtf(ax*ax+ay*ay+az*az+1e-12f);
  const float inv = 1.f/r;
  const float X = ax*inv, Yv = ay*inv, Z = az*inv;
  if (lane==0){
    s_ym[0]=0.28209479f;
    s_ym[1]=0.48860251f*Yv; s_ym[2]=0.48860251f*Z; s_ym[3]=0.48860251f*X;
    s_ym[4]=1.09254843f*X*Yv; s_ym[5]=1.09254843f*Yv*Z; s_ym[6]=0.31539157f*(3.f*Z*Z-1.f);
    s_ym[7]=1.09254843f*X*Z; s_ym[8]=0.54627422f*(X*X-Yv*Yv);
  }
  float g[12];
  const float tt = r*(11.f/10.f);
  #pragma unroll
  for (int bb=0;bb<12;bb++){ const float d = tt-(float)bb; g[bb]=expf(-d*d); }
  #pragma unroll
  for (int rr=0;rr<3;rr++){
    if (lane < 60){
      const int p = rr*5 + lane/12;
      const int jj = lane%12;
      float acc = rb1[p*12+jj];
      #pragma unroll
      for (int bb=0;bb<12;bb++) acc += g[bb]*rw1[(p*12+bb)*12+jj];
      s_h1[p*12+jj] = fmaxf(acc,0.f);
    }
  }
  __syncthreads();
  for (int t3=lane; t3<TOTD; t3+=64){
    const int2 d = dtab[t3];
    const int base = d.x;
    const int cnt = d.y & 0xff, str=(d.y>>8)&0xff, yb = d.y>>16;
    float acc=0.f;
    for (int t=0;t<cnt;t++) acc += cgws[base+t*str]*s_ym[yb+t];
    s_D[t3]=acc;
  }
  __syncthreads();
  const int c = lane;
  if (c >= 40) return;
  float xi[9];
  const float* xb = outs + (size_t)src*360 + c;
  #pragma unroll
  for (int mm=0;mm<9;mm++) xi[mm] = xb[mm*40];
#define DP(P) do_path<P>(rb2,rw2,s_h1,s_D,xi,c,n4,tmp0,tmp1,tmp2)
  DP(0);DP(1);DP(2);DP(3);DP(4);DP(5);DP(6);DP(7);DP(8);DP(9);DP(10);DP(11);DP(12);DP(13);DP(14);
#undef DP
}

// ---- K5: head — norms, lin40/41/42, gated nonlins, fused MLP, output assembly ----
__global__ __launch_bounds__(256) void k_head(const float* __restrict__ tmp0, const float* __restrict__ tmp1,
    const float* __restrict__ tmp2,
    const float* __restrict__ w40, const float* __restrict__ b40,
    const float* __restrict__ w41, const float* __restrict__ w42,
    const float* __restrict__ d1w, const float* __restrict__ d1b,
    const float* __restrict__ cw, const float* __restrict__ cbp,
    float* __restrict__ out){
  __shared__ float st0[120], st1[720], st2[1200];
  __shared__ float h0s[40], v1[120], v2[200];
  __shared__ float red[256];
  const int b = blockIdx.x, tid = threadIdx.x;
  for (int t=tid; t<120; t+=256) st0[t]=tmp0[(size_t)b*120+t];
  for (int t=tid; t<720; t+=256) st1[t]=tmp1[(size_t)b*720+t];
  for (int t=tid; t<1200; t+=256) st2[t]=tmp2[(size_t)b*1200+t];
  __syncthreads();
  if (tid < 240){
    const int s = tid/40, c = tid - s*40;
    float a0=st1[s*120+c], a1=st1[s*120+40+c], a2=st1[s*120+80+c];
    const float i1 = 1.f/(sqrtf(a0*a0+a1*a1+a2*a2)+1e-8f);
    st1[s*120+c]=a0*i1; st1[s*120+40+c]=a1*i1; st1[s*120+80+c]=a2*i1;
    float ss=0.f;
    #pragma unroll
    for (int k=0;k<5;k++){ const float v=st2[s*200+k*40+c]; ss+=v*v; }
    const float i2 = 1.f/(sqrtf(ss)+1e-8f);
    #pragma unroll
    for (int k=0;k<5;k++) st2[s*200+k*40+c]*=i2;
  }
  __syncthreads();
  if (tid < 200){
    const int o=tid/5, k=tid-o*5;
    float acc=0.f;
    for (int s=0;s<6;s++){
      const float* sp = st2 + s*200 + k*40;
      const float* wr = w42 + o*240 + s*40;
      #pragma unroll
      for (int c=0;c<40;c++) acc += sp[c]*wr[c];
    }
    v2[tid]=acc;
  }
  if (tid < 120){
    const int o=tid/3, k=tid-o*3;
    float acc=0.f;
    for (int s=0;s<6;s++){
      const float* sp = st1 + s*120 + k*40;
      const float* wr = w41 + o*240 + s*40;
      #pragma unroll
      for (int c=0;c<40;c++) acc += sp[c]*wr[c];
    }
    v1[tid]=acc;
  }
  if (tid < 40){
    float acc = b40[tid];
    const float* wr = w40 + tid*120;
    for (int C=0;C<120;C++) acc += st0[C]*wr[C];
    h0s[tid] = sspf(acc);
  }
  __syncthreads();
  if (tid < 40){
    const int o=tid;
    const float q0=v1[o*3],q1=v1[o*3+1],q2=v1[o*3+2];
    const float nn=sqrtf(q0*q0+q1*q1+q2*q2+1e-12f);
    const float sc=sspf(nn)/(nn+1e-8f);
    float* orow = out + (size_t)b*321;
    orow[1+o*3]=q0*sc; orow[2+o*3]=q1*sc; orow[3+o*3]=q2*sc;
  } else if (tid >= 64 && tid < 104){
    const int o=tid-64;
    float q[5]; float ss=1e-12f;
    #pragma unroll
    for (int k=0;k<5;k++){ q[k]=v2[o*5+k]; ss+=q[k]*q[k]; }
    const float nn=sqrtf(ss);
    const float sc=sspf(nn)/(nn+1e-8f);
    float* orow = out + (size_t)b*321;
    #pragma unroll
    for (int k=0;k<5;k++) orow[121+o*5+k]=q[k]*sc;
  }
  float contrib=0.f;
  if (tid < 250){
    float acc=d1b[tid];
    const float* wr=d1w+tid*40;
    #pragma unroll
    for (int cc=0;cc<40;cc++) acc += h0s[cc]*wr[cc];
    const float hj = acc>0.f? acc : expf(acc)-1.f;
    contrib = hj*cw[tid];
  }
  red[tid]=contrib;
  __syncthreads();
  for (int s=128;s>0;s>>=1){ if(tid<s) red[tid]+=red[tid+s]; __syncthreads(); }
  if (tid==0) out[(size_t)b*321] = red[0] + cbp[0];
}

extern "C" void kernel_launch(void* const* d_in, const int* in_sizes, int n_in,
                              void* d_out, int out_size, void* d_ws, size_t ws_size,
                              hipStream_t stream){
  const float* x    =(const float*)d_in[0];
  const int*   ei   =(const int*)d_in[1];
  const float* ea   =(const float*)d_in[2];
  const float* l1w  =(const float*)d_in[3];
  const float* l1b  =(const float*)d_in[4];
  const float* c1rw1=(const float*)d_in[5];
  const float* c1rb1=(const float*)d_in[6];
  const float* c1rw2=(const float*)d_in[7];
  const float* c1rb2=(const float*)d_in[8];
  const float* l2w  =(const float*)d_in[9];
  const float* l2b0 =(const float*)d_in[10];
  const float* l3w  =(const float*)d_in[11];
  const float* l3b0 =(const float*)d_in[12];
  const float* c2rw1=(const float*)d_in[13];
  const float* c2rb1=(const float*)d_in[14];
  const float* c2rw2=(const float*)d_in[15];
  const float* c2rb2=(const float*)d_in[16];
  const float* w40  =(const float*)d_in[17];
  const float* b40  =(const float*)d_in[18];
  const float* w41  =(const float*)d_in[19];
  const float* w42  =(const float*)d_in[20];
  const float* d1w  =(const float*)d_in[21];
  const float* d1b  =(const float*)d_in[22];
  const float* d2w  =(const float*)d_in[23];
  const float* d2b  =(const float*)d_in[24];
  const float* d3w  =(const float*)d_in[25];
  const float* d3b  =(const float*)d_in[26];
  const int N = in_sizes[0]/20;
  const int E = in_sizes[1]/2;
  const int NCA = N/4;
  float* ws = (float*)d_ws;
  const size_t OFF_OUTS = OFF_H + (size_t)N*40;
  const size_t OFF_TMP0 = OFF_OUTS + (size_t)N*360;
  const size_t OFF_TMP1 = OFF_TMP0 + (size_t)NCA*120;
  const size_t OFF_TMP2 = OFF_TMP1 + (size_t)NCA*720;
  hipMemsetAsync(ws + OFF_OUTS, 0, ((size_t)N*360 + (size_t)NCA*2040)*sizeof(float), stream);
  k_setup<<<1,256,0,stream>>>(d2w,d2b,d3w,d3b,ws);
  k_embed<<<(N*40+255)/256,256,0,stream>>>(x,l1w,l1b,ws+OFF_H,N);
  k_conv1<<<(E+3)/4,256,0,stream>>>(ei,ea,c1rw1,c1rb1,c1rw2,c1rb2, ws+OFF_H, ws+OFF_OUTS, E);
  k_node<<<(N+3)/4,256,0,stream>>>(ws+OFF_OUTS, l2w,l2b0,l3w,l3b0, N);
  k_conv2<<<E,64,0,stream>>>(ei,ea,c2rw1,c2rb1,c2rw2,c2rb2, ws+OFF_OUTS, ws+OFF_CG,
                             (const int2*)(ws+OFF_DT), ws+OFF_TMP0, ws+OFF_TMP1, ws+OFF_TMP2, E);
  k_head<<<NCA,256,0,stream>>>(ws+OFF_TMP0, ws+OFF_TMP1, ws+OFF_TMP2, w40,b40,w41,w42,
                               d1w,d1b, ws+OFF_CW, ws+OFF_CB, (float*)d_out);
  (void)n_in; (void)out_size; (void)ws_size;
}